// Round 2
// baseline (520.808 us; speedup 1.0000x reference)
//
#include <hip/hip_runtime.h>
#include <cstdint>

// ---------------------------------------------------------------------------
// NVFP4 fake-quant GEMM: out = fq4(x) @ fq4(w)^T + bias
// fq4: per-16-group (along K) scale = e4m3_rt(amax/6), values on e2m1 grid.
// dq = q*scale is EXACT in bf16, so we quantize into bf16 buffers in d_ws and
// run a bf16-MFMA GEMM.
//
// GEMM v3: 256x256 tile, BK=64, 8 waves, mfma_f32_32x32x16_bf16, NO intra-
// tile barriers (2 per K-tile), k-step-pipelined fragment loads so the LDS
// read pipe (~2300 cyc/tile) overlaps the MFMA pipe (~2064 cyc/tile) instead
// of serializing (round-1: 5100 cyc/tile). Counted vmcnt(8); raw s_barrier
// only (never __syncthreads: it drains vmcnt(0) and kills the pipeline).
// ---------------------------------------------------------------------------

typedef __attribute__((ext_vector_type(8))) __bf16 bf16x8;
typedef __attribute__((ext_vector_type(16))) float f32x16;

typedef __attribute__((address_space(1))) void gvoid;
typedef __attribute__((address_space(3))) void lvoid;

// Exact fp8 e4m3fn round-trip for x >= 0, x well below 448.
__device__ __forceinline__ float fp8_e4m3_rt(float x) {
    if (x < 0.015625f) {
        return __builtin_rintf(x * 512.0f) * (1.0f / 512.0f);
    }
    unsigned u = __float_as_uint(x);
    unsigned lsb = (u >> 20) & 1u;
    u = (u + 0x7FFFFu + lsb) & ~0xFFFFFu;
    return __uint_as_float(u);
}

// ---------------------------------------------------------------------------
// Quant: one fused launch over xq||wq (contiguous in d_ws). 2 quads/thread.
// Bucket of fl32(|v|/scale) on the e2m1 threshold chain WITHOUT any division:
//   ref condition  fl(|v|/s) < t   ⟺   |v|/s < t - u/2   (ties impossible:
//   s has ≤4-bit mantissa, t-u/2 has an odd ≥25-bit mantissa, product never
//   representable in 24 bits)   ⟺   fmaf(-s, t, |v|) < -s*(u/2).
//   Near the boundary the fma is exact by Sterbenz; far away the sign is
//   robust. s==0 falls out automatically (all compares false -> q=6, dq=0).
// ---------------------------------------------------------------------------
__device__ __forceinline__ uint2 quant_quad(float4 v) {
    float ax = fabsf(v.x), ay = fabsf(v.y), az = fabsf(v.z), aw = fabsf(v.w);
    float a = fmaxf(fmaxf(ax, ay), fmaxf(az, aw));
    a = fmaxf(a, __shfl_xor(a, 1));
    a = fmaxf(a, __shfl_xor(a, 2));
    float scale = fp8_e4m3_rt(a / 6.0f);     // exact fp32 div, like ref
    float sN = -scale;
    // -scale * (half-ulp below each threshold); exact products.
    float n0 = sN * 0x1p-27f;   // t=0.25
    float n1 = sN * 0x1p-25f;   // t=0.75
    float n2 = sN * 0x1p-24f;   // t=1.25, 1.75
    float n4 = sN * 0x1p-23f;   // t=2.5, 3.5
    float n6 = sN * 0x1p-22f;   // t=5
    float e[4] = {v.x, v.y, v.z, v.w};
    unsigned r[4];
    #pragma unroll
    for (int i = 0; i < 4; ++i) {
        float av = fabsf(e[i]);
        float q =
            fmaf(sN, 0.25f, av) < n0 ? 0.0f :
            fmaf(sN, 0.75f, av) < n1 ? 0.5f :
            fmaf(sN, 1.25f, av) < n2 ? 1.0f :
            fmaf(sN, 1.75f, av) < n2 ? 1.5f :
            fmaf(sN, 2.5f,  av) < n4 ? 2.0f :
            fmaf(sN, 3.5f,  av) < n4 ? 3.0f :
            fmaf(sN, 5.0f,  av) < n6 ? 4.0f : 6.0f;
        float dq = q * scale;                                // exact, >= 0
        r[i] = (__float_as_uint(dq) | (__float_as_uint(e[i]) & 0x80000000u)) >> 16;
    }
    uint2 o;
    o.x = r[0] | (r[1] << 16);
    o.y = r[2] | (r[3] << 16);
    return o;
}

__global__ __launch_bounds__(256)
void quant_fp4_fused(const float* __restrict__ x, const float* __restrict__ w,
                     uint16_t* __restrict__ out, int xquads, int totquads) {
    const int half = totquads >> 1;          // multiple of 4 (group-aligned)
    const int t0 = blockIdx.x * 256 + threadIdx.x;
    uint2* o2 = (uint2*)out;
    if (t0 < half) {
        const float4* s0 = (t0 < xquads) ? ((const float4*)x) + t0
                                         : ((const float4*)w) + (t0 - xquads);
        o2[t0] = quant_quad(*s0);
    }
    const int q1 = t0 + half;
    if (q1 < totquads) {
        const float4* s1 = (q1 < xquads) ? ((const float4*)x) + q1
                                         : ((const float4*)w) + (q1 - xquads);
        o2[q1] = quant_quad(*s1);
    }
}

// ---------------------------------------------------------------------------
// bf16 GEMM, C[M,N] = A[M,K] * B[N,K]^T + bias.
// 256x256 tile, BK=64, 512 threads = 8 waves (2M x 4N), per-wave 128x64 via
// a 4x2 grid of 32x32 accumulators (f32x16 each = 128 AGPR).
// LDS: 2 buffers x (A[256][64] + B[256][64]) bf16 = 128 KiB, XOR-swizzled:
// logical (row,k) at elem row*64 + (k ^ ((row&7)<<3)); staging writes linear
// chunks with the inverse-permuted global source (same involution).
// Fragments (32x32x16): row = lane&31, k = (lane>>5)*8 + j;
// C/D: col = lane&31, row = (reg&3) + 8*(reg>>2) + 4*(lane>>5)  [m74/m101].
// ---------------------------------------------------------------------------
#define BM 256
#define BN 256
#define BK 64
#define THREADS 512

#define STG_A(bb, i, kk)                                                     \
    __builtin_amdgcn_global_load_lds((gvoid*)(Aq + (size_t)offA[i] + (kk)),  \
        (lvoid*)&lds[bb][0][ldsU + (i) * 4096], 16, 0, 0)
#define STG_B(bb, i, kk)                                                     \
    __builtin_amdgcn_global_load_lds((gvoid*)(Bq + (size_t)offB[i] + (kk)),  \
        (lvoid*)&lds[bb][1][ldsU + (i) * 4096], 16, 0, 0)

__global__ __launch_bounds__(THREADS, 2)
void gemm_w4a4(const uint16_t* __restrict__ Aq, const uint16_t* __restrict__ Bq,
               const float* __restrict__ bias, float* __restrict__ C,
               int M, int N, int K) {
    __shared__ __align__(16) uint16_t lds[2][2][BM * BK];

    const int tid  = threadIdx.x;
    const int wave = tid >> 6;
    const int lane = tid & 63;
    const int wm   = wave >> 2;            // 0..1  (m half)
    const int wn   = wave & 3;             // 0..3  (n quarter)
    const int l31  = lane & 31;
    const int hi8  = (lane >> 5) << 3;     // k subgroup: 0 or 8
    const int rsw  = (lane & 7) << 3;      // row-swizzle XOR (elem units)

    // Swizzled k elem offsets for the 4 k-steps of a BK=64 tile.
    int kx[4];
    #pragma unroll
    for (int ks = 0; ks < 4; ++ks) kx[ks] = (ks * 16 + hi8) ^ rsw;

    const int aRow = ((wm << 7) + l31) << 6;   // elem offset of A frag row
    const int bRow = ((wn << 6) + l31) << 6;   // elem offset of B frag row
    const int ldsU = wave << 9;                // wave-uniform stage base (elems)

    // ---- tile decomposition + bijective XCD swizzle (T1, m204) ----
    const int ntm = M >> 8, ntn = N >> 8, nwg = ntm * ntn;
    const int bid = blockIdx.x;
    const int q8 = nwg >> 3, r8 = nwg & 7;
    const int xcd = bid & 7;
    const int wgid = (xcd < r8 ? xcd * (q8 + 1) : r8 * (q8 + 1) + (xcd - r8) * q8)
                     + (bid >> 3);
    const int mBase = (wgid % ntm) << 8;   // column-major: XCD shares B panel
    const int nBase = (wgid / ntm) << 8;
    (void)ntn;

    // ---- staging source offsets (inverse-swizzled, loop-invariant) ----
    // chunk c = i*512 + tid -> linear LDS elems [c*8, c*8+8);
    // holds logical row = c>>3, k = ((c&7) ^ (row&7))*8 .. +7
    uint32_t offA[4], offB[4];
    #pragma unroll
    for (int i = 0; i < 4; ++i) {
        const int c   = i * THREADS + tid;
        const int row = c >> 3;
        const int kc  = ((c & 7) ^ (row & 7)) << 3;
        offA[i] = (uint32_t)(mBase + row) * (uint32_t)K + (uint32_t)kc;
        offB[i] = (uint32_t)(nBase + row) * (uint32_t)K + (uint32_t)kc;
    }

    const int nt = K / BK;

    // ---- prologue: stage tile 0 into buf 0 ----
    #pragma unroll
    for (int i = 0; i < 4; ++i) STG_A(0, i, 0);
    #pragma unroll
    for (int i = 0; i < 4; ++i) STG_B(0, i, 0);

    f32x16 acc[4][2] = {};

    for (int tk = 0; tk < nt; ++tk) {
        const int bb = tk & 1;
        const uint16_t* lA = &lds[bb][0][0];
        const uint16_t* lB = &lds[bb][1][0];

        // barrier1: all waves done reading buf[bb^1] (tile tk-1) -> safe to
        // overwrite it with tile tk+1.
        asm volatile("" ::: "memory");
        __builtin_amdgcn_s_barrier();
        asm volatile("" ::: "memory");

        if (tk + 1 < nt) {
            const int kk = (tk + 1) * BK;
            #pragma unroll
            for (int i = 0; i < 4; ++i) STG_A(bb ^ 1, i, kk);
            #pragma unroll
            for (int i = 0; i < 4; ++i) STG_B(bb ^ 1, i, kk);
            // 16 outstanding: tile tk (oldest 8) + tile tk+1 (newest 8).
            asm volatile("s_waitcnt vmcnt(8)" ::: "memory");
        } else {
            asm volatile("s_waitcnt vmcnt(0)" ::: "memory");
        }
        // barrier2: every wave has passed its vmcnt -> tile tk fully in LDS.
        __builtin_amdgcn_s_barrier();
        asm volatile("" ::: "memory");

        // ---- k-step-pipelined compute: no barriers, reads of step ks+1
        //      fly while MFMAs of step ks execute ----
        bf16x8 aC[4], bC[2], aN[4], bN[2];
        #pragma unroll
        for (int mi = 0; mi < 4; ++mi)
            aC[mi] = *(const bf16x8*)&lA[aRow + mi * 2048 + kx[0]];
        #pragma unroll
        for (int ni = 0; ni < 2; ++ni)
            bC[ni] = *(const bf16x8*)&lB[bRow + ni * 2048 + kx[0]];

        #pragma unroll
        for (int ks = 0; ks < 4; ++ks) {
            if (ks < 3) {
                #pragma unroll
                for (int mi = 0; mi < 4; ++mi)
                    aN[mi] = *(const bf16x8*)&lA[aRow + mi * 2048 + kx[ks + 1]];
                #pragma unroll
                for (int ni = 0; ni < 2; ++ni)
                    bN[ni] = *(const bf16x8*)&lB[bRow + ni * 2048 + kx[ks + 1]];
            }
            __builtin_amdgcn_s_setprio(1);
            #pragma unroll
            for (int mi = 0; mi < 4; ++mi)
                #pragma unroll
                for (int ni = 0; ni < 2; ++ni)
                    acc[mi][ni] = __builtin_amdgcn_mfma_f32_32x32x16_bf16(
                        aC[mi], bC[ni], acc[mi][ni], 0, 0, 0);
            __builtin_amdgcn_s_setprio(0);
            if (ks < 3) {
                #pragma unroll
                for (int mi = 0; mi < 4; ++mi) aC[mi] = aN[mi];
                #pragma unroll
                for (int ni = 0; ni < 2; ++ni) bC[ni] = bN[ni];
            }
        }
    }

    // ---- epilogue: 32x32 C/D layout: col = lane&31,
    //      row = (reg&3) + 8*(reg>>2) + 4*(lane>>5) ----
    #pragma unroll
    for (int ni = 0; ni < 2; ++ni) {
        const int col = nBase + (wn << 6) + ni * 32 + l31;
        const float bj = bias[col];
        #pragma unroll
        for (int mi = 0; mi < 4; ++mi) {
            const int rowb = mBase + (wm << 7) + mi * 32 + ((lane >> 5) << 2);
            #pragma unroll
            for (int r = 0; r < 16; ++r) {
                const int row = rowb + (r & 3) + ((r >> 2) << 3);
                C[(size_t)row * N + col] = acc[mi][ni][r] + bj;
            }
        }
    }
}

extern "C" void kernel_launch(void* const* d_in, const int* in_sizes, int n_in,
                              void* d_out, int out_size, void* d_ws, size_t ws_size,
                              hipStream_t stream) {
    const float* x    = (const float*)d_in[0];
    const float* w    = (const float*)d_in[1];
    const float* bias = (const float*)d_in[2];
    float* out = (float*)d_out;

    const int N = in_sizes[2];            // bias length
    const int K = in_sizes[1] / N;        // weight is [N,K]
    const int M = in_sizes[0] / K;        // x is [M,K]

    uint16_t* xq = (uint16_t*)d_ws;                 // M*K bf16
    uint16_t* wq = xq + (size_t)M * K;              // N*K bf16 (contiguous!)
    (void)wq;

    const int xquads = (M * K) / 4;
    const int totquads = xquads + (N * K) / 4;
    const int half = totquads / 2;
    quant_fp4_fused<<<(half + 255) / 256, 256, 0, stream>>>(x, w, xq, xquads, totquads);

    const int nwg = (M >> 8) * (N >> 8);
    gemm_w4a4<<<nwg, THREADS, 0, stream>>>(xq, wq, bias, out, M, N, K);
}